// Round 15
// baseline (174.371 us; speedup 1.0000x reference)
//
#include <hip/hip_runtime.h>
#include <hip/hip_bf16.h>

#define DEV __device__ __forceinline__

typedef unsigned short u16;
typedef unsigned int u32;
typedef __attribute__((ext_vector_type(8))) short short8;
typedef __attribute__((ext_vector_type(4))) float f32x4;

DEV u16 f2bf(float f) {
  __hip_bfloat16 h = __float2bfloat16(f);   // RNE
  return *(u16*)&h;
}
DEV float bf2f_s(short s) { return __uint_as_float(((u32)(u16)s) << 16); }

#define NB 8
#define NH 6
#define CTOT 192
#define HW 16384
#define VTS 34     // k3 LDS n-row stride (u16): 17 dwords, coprime 32 banks
#define LSTR 136   // kconv LDS row stride (f32): 4 pad + 128 px + 4 spare; %32=8 -> row bank shift

// ---------------------------------------------------------------------------
// KCONV v5: LDS-staged conv. R11-R14 proved the register allocator defeats
// every global->reg pipeline (VGPR pinned 28-60, VALUBusy ~28%, ~100us).
// New structure: stage a 66x128 f32 slab (one channel, 64-row half + halo)
// into padded LDS with one coalesced pass, barrier once, then convolve from
// LDS with aligned reads (compiler pipelines lgkmcnt well). 4 px/lane.
// LDS px c at float c+4: b128 @ 4j+4, b32 @ 4j+3, b32 @ 4j+8 all aligned.
// 35.9KB LDS -> 4 blocks/CU (16 waves). kv blocks emit k AND v from one y.
// grid 6144 = (q|kv) x 8b x 192ch x 2 row-halves.
// ---------------------------------------------------------------------------
__global__ __launch_bounds__(256) void kconv(
    const float* __restrict__ x, const float* __restrict__ y,
    const float* __restrict__ wdw,
    u16* __restrict__ qws, u16* __restrict__ kws, u16* __restrict__ vws)
{
  __shared__ __align__(16) float lds[66 * LSTR];
  const int t = threadIdx.x, lane = t & 63, w = t >> 6;
  const int bx   = blockIdx.x;
  const int iskv = bx & 1;
  const int rest = bx >> 1;          // 0..3071
  const int chp  = rest & 1;
  const int task = rest >> 1;        // 0..1535
  const int b  = task / 192;
  const int gc = task % 192;
  const int r0 = chp * 64;

  const float* __restrict__ in =
      (iskv ? y : x) + (((size_t)(b * CTOT + gc)) << 14);

  float w0[9], w1[9];
  if (!iskv) {
#pragma unroll
    for (int i = 0; i < 9; ++i) w0[i] = wdw[gc * 9 + i];
  } else {
#pragma unroll
    for (int i = 0; i < 9; ++i) {
      w0[i] = wdw[(CTOT + gc) * 9 + i];       // k
      w1[i] = wdw[(2 * CTOT + gc) * 9 + i];   // v
    }
  }

  // zero the horizontal edge pads actually read: float 3 (px -1), 132 (px 128)
  if (t < 132) {
    const int row = t >> 1;
    lds[row * LSTR + ((t & 1) ? 132 : 3)] = 0.f;
  }
  // stage 66 rows x 128 px (f32), coalesced float4; OOB rows -> zero
#pragma unroll
  for (int i = 0; i < 9; ++i) {
    const int idx = i * 256 + t;
    if (idx < 2112) {                      // 66 rows * 32 float4
      const int row = idx >> 5, c4 = idx & 31;
      const int grow = r0 - 1 + row;
      float4 v = (grow >= 0 && grow < 128)
          ? *(const float4*)(in + grow * 128 + c4 * 4)
          : make_float4(0.f, 0.f, 0.f, 0.f);
      *(float4*)&lds[row * LSTR + 4 + c4 * 4] = v;
    }
  }
  __syncthreads();

  const int j    = lane & 31;          // px group: px 4j..4j+3
  const int half = lane >> 5;          // 0: even row of pair, 1: odd
  u16* __restrict__ out0 =
      (iskv ? kws : qws) + (((size_t)(b * CTOT + gc)) << 14);
  u16* __restrict__ out1 = vws + (((size_t)(b * CTOT + gc)) << 14);

#pragma unroll
  for (int i = 0; i < 8; ++i) {
    const int lrow = w * 16 + i * 2 + half;    // local out row 0..63
    const int r = r0 + lrow;

    float  lt[3], rt[3];
    float4 md[3];
#pragma unroll
    for (int dr = 0; dr < 3; ++dr) {
      const int base = (lrow + dr) * LSTR + 4 * j;
      lt[dr] = lds[base + 3];
      md[dr] = *(const float4*)&lds[base + 4];
      rt[dr] = lds[base + 8];
    }

    // class 0 (q or k)
    {
      float o0 = 0.f, o1 = 0.f, o2 = 0.f, o3 = 0.f;
#pragma unroll
      for (int dr = 0; dr < 3; ++dr) {
        const float a = lt[dr], b0 = md[dr].x, c = md[dr].y,
                    d = md[dr].z, e = md[dr].w, f = rt[dr];
        o0 = fmaf(w0[dr * 3 + 0], a,  o0); o0 = fmaf(w0[dr * 3 + 1], b0, o0); o0 = fmaf(w0[dr * 3 + 2], c, o0);
        o1 = fmaf(w0[dr * 3 + 0], b0, o1); o1 = fmaf(w0[dr * 3 + 1], c,  o1); o1 = fmaf(w0[dr * 3 + 2], d, o1);
        o2 = fmaf(w0[dr * 3 + 0], c,  o2); o2 = fmaf(w0[dr * 3 + 1], d,  o2); o2 = fmaf(w0[dr * 3 + 2], e, o2);
        o3 = fmaf(w0[dr * 3 + 0], d,  o3); o3 = fmaf(w0[dr * 3 + 1], e,  o3); o3 = fmaf(w0[dr * 3 + 2], f, o3);
      }
      const u32 p01 = ((u32)f2bf(o1) << 16) | (u32)f2bf(o0);
      const u32 p23 = ((u32)f2bf(o3) << 16) | (u32)f2bf(o2);
      *(uint2*)(out0 + r * 128 + 4 * j) = make_uint2(p01, p23);
    }
    // class 1 (v), kv blocks only
    if (iskv) {
      float o0 = 0.f, o1 = 0.f, o2 = 0.f, o3 = 0.f;
#pragma unroll
      for (int dr = 0; dr < 3; ++dr) {
        const float a = lt[dr], b0 = md[dr].x, c = md[dr].y,
                    d = md[dr].z, e = md[dr].w, f = rt[dr];
        o0 = fmaf(w1[dr * 3 + 0], a,  o0); o0 = fmaf(w1[dr * 3 + 1], b0, o0); o0 = fmaf(w1[dr * 3 + 2], c, o0);
        o1 = fmaf(w1[dr * 3 + 0], b0, o1); o1 = fmaf(w1[dr * 3 + 1], c,  o1); o1 = fmaf(w1[dr * 3 + 2], d, o1);
        o2 = fmaf(w1[dr * 3 + 0], c,  o2); o2 = fmaf(w1[dr * 3 + 1], d,  o2); o2 = fmaf(w1[dr * 3 + 2], e, o2);
        o3 = fmaf(w1[dr * 3 + 0], d,  o3); o3 = fmaf(w1[dr * 3 + 1], e,  o3); o3 = fmaf(w1[dr * 3 + 2], f, o3);
      }
      const u32 p01 = ((u32)f2bf(o1) << 16) | (u32)f2bf(o0);
      const u32 p23 = ((u32)f2bf(o3) << 16) | (u32)f2bf(o2);
      *(uint2*)(out1 + r * 128 + 4 * j) = make_uint2(p01, p23);
    }
  }
}

// ---------------------------------------------------------------------------
// K2a (verified R3): per (b,head) gram[c][d] = sum_n q[c][n]*k[d][n] via MFMA,
// plus sum-of-squares. grid 48x16 p-tiles, f32-atomic partials (pre-zeroed).
// ---------------------------------------------------------------------------
__global__ __launch_bounds__(256) void k2a_gram(
    const u16* __restrict__ qws, const u16* __restrict__ kws,
    float* __restrict__ gram, float* __restrict__ sqq, float* __restrict__ sqk)
{
  const int t = threadIdx.x, l = t & 63, w = t >> 6;
  const int bh = blockIdx.x >> 4, tile = blockIdx.x & 15;
  const int p0 = tile * 1024 + w * 256;
  const u16* qb = qws + (((size_t)bh) << 19);
  const u16* kb = kws + (((size_t)bh) << 19);
  const int row = l & 15;
  const int kq  = (l >> 4) * 8;

  f32x4 acc[2][2] = {};
  float sq[2] = {0.f, 0.f}, sk[2] = {0.f, 0.f};

  for (int ks = 0; ks < 8; ++ks) {
    const int p = p0 + ks * 32 + kq;
    short8 av[2], bv[2];
#pragma unroll
    for (int tc = 0; tc < 2; ++tc) {
      av[tc] = *(const short8*)(qb + (((size_t)(tc * 16 + row)) << 14) + p);
      bv[tc] = *(const short8*)(kb + (((size_t)(tc * 16 + row)) << 14) + p);
    }
#pragma unroll
    for (int tc = 0; tc < 2; ++tc) {
#pragma unroll
      for (int j = 0; j < 8; ++j) {
        float fa = bf2f_s(av[tc][j]); sq[tc] = fmaf(fa, fa, sq[tc]);
        float fb = bf2f_s(bv[tc][j]); sk[tc] = fmaf(fb, fb, sk[tc]);
      }
    }
#pragma unroll
    for (int tc = 0; tc < 2; ++tc)
#pragma unroll
      for (int td = 0; td < 2; ++td)
        acc[tc][td] = __builtin_amdgcn_mfma_f32_16x16x32_bf16(av[tc], bv[td], acc[tc][td], 0, 0, 0);
  }

#pragma unroll
  for (int tc = 0; tc < 2; ++tc)
#pragma unroll
    for (int td = 0; td < 2; ++td)
#pragma unroll
      for (int rr = 0; rr < 4; ++rr) {
        int c = tc * 16 + (l >> 4) * 4 + rr;
        int d = td * 16 + row;
        atomicAdd(gram + (size_t)bh * 1024 + c * 32 + d, acc[tc][td][rr]);
      }

#pragma unroll
  for (int tc = 0; tc < 2; ++tc) {
    sq[tc] += __shfl_xor(sq[tc], 16);
    sq[tc] += __shfl_xor(sq[tc], 32);
    sk[tc] += __shfl_xor(sk[tc], 16);
    sk[tc] += __shfl_xor(sk[tc], 32);
  }
  if ((l >> 4) == 0) {
#pragma unroll
    for (int tc = 0; tc < 2; ++tc) {
      atomicAdd(sqq + bh * 32 + tc * 16 + row, sq[tc]);
      atomicAdd(sqk + bh * 32 + tc * 16 + row, sk[tc]);
    }
  }
}

// ---------------------------------------------------------------------------
// K2b: logits = gram/(|q||k|)*temp, row-softmax, fold 1x1 proj:
//   W2[b][o][h*32+d] = sum_c wp[o][h*32+c] * A[c][d]  (bf16 out)
// ---------------------------------------------------------------------------
__global__ __launch_bounds__(256) void k2b_w2(
    const float* __restrict__ gram, const float* __restrict__ sqq,
    const float* __restrict__ sqk, const float* __restrict__ wp,
    const float* __restrict__ temp, u16* __restrict__ W2)
{
  __shared__ float Ls[32][33];
  __shared__ float As[32][33];
  __shared__ float wl[192 * 32];
  __shared__ float nq[32], nk[32];
  const int t = threadIdx.x;
  const int bh = blockIdx.x, b = bh / 6, h = bh % 6;
  const float tmp = temp[h];
  if (t < 32) nq[t] = fmaxf(sqrtf(sqq[bh * 32 + t]), 1e-12f);
  else if (t < 64) nk[t - 32] = fmaxf(sqrtf(sqk[bh * 32 + t - 32]), 1e-12f);
  __syncthreads();
#pragma unroll
  for (int i = 0; i < 4; ++i) {
    int idx = i * 256 + t, c = idx >> 5, d = idx & 31;
    Ls[c][d] = gram[(size_t)bh * 1024 + idx] / (nq[c] * nk[d]) * tmp;
  }
  __syncthreads();
  if (t < 32) {
    float m = -1e30f;
#pragma unroll
    for (int d = 0; d < 32; ++d) m = fmaxf(m, Ls[t][d]);
    float s = 0.f;
#pragma unroll
    for (int d = 0; d < 32; ++d) s += expf(Ls[t][d] - m);
    float inv = 1.0f / s;
#pragma unroll
    for (int d = 0; d < 32; ++d) As[t][d] = expf(Ls[t][d] - m) * inv;
  }
  for (int i = 0; i < 24; ++i) {
    int idx = i * 256 + t, o = idx >> 5, c = idx & 31;
    wl[idx] = wp[o * 192 + h * 32 + c];
  }
  __syncthreads();
  for (int i = 0; i < 24; ++i) {
    int idx = i * 256 + t, o = idx >> 5, d = idx & 31;
    float a = 0.f;
#pragma unroll
    for (int c = 0; c < 32; ++c) a = fmaf(wl[o * 32 + c], As[c][d], a);
    W2[((size_t)(b * 192 + o)) * 192 + h * 32 + d] = f2bf(a);
  }
}

// ---------------------------------------------------------------------------
// K3: out[b][o][n] = sum_c W2[b][o][c] * v[b][c][n], MFMA 16x16x32 bf16.
// v in natural [b][c][n]; per ks-step stage 32x128 tile -> LDS transpose.
// Epilogue: LDS-transpose C so global stores are contiguous float4 runs.
// ---------------------------------------------------------------------------
__global__ __launch_bounds__(256) void k3_gemm(
    const u16* __restrict__ W2, const u16* __restrict__ vnat,
    float* __restrict__ out)
{
  __shared__ __align__(16) u16 b_tile[128 * VTS];
  __shared__ __align__(16) float cout[32 * 132];
  const int t = threadIdx.x, l = t & 63, w = t >> 6;
  const int bx = blockIdx.x;
  const int b  = bx >> 7, nb = bx & 127;
  const int arow = l & 15;
  const int kq8  = (l >> 4) * 8;
  const u16* w2b = W2 + (size_t)b * 192 * 192;
  const u16* vb  = vnat + ((size_t)b * CTOT) * HW;
  const int n0 = nb * 128;

  f32x4 acc[12][2] = {};

  for (int ks = 0; ks < 6; ++ks) {
    if (ks > 0) __syncthreads();
#pragma unroll
    for (int r2 = 0; r2 < 2; ++r2) {
      const int ch   = (t >> 4) + r2 * 16;
      const int nseg = (t & 15) * 8;
      short8 vv = *(const short8*)(vb + (size_t)(ks * 32 + ch) * HW + n0 + nseg);
#pragma unroll
      for (int j = 0; j < 8; ++j) b_tile[(nseg + j) * VTS + ch] = (u16)vv[j];
    }
    __syncthreads();

    short8 bf[2];
#pragma unroll
    for (int nt = 0; nt < 2; ++nt)
      bf[nt] = *(const short8*)&b_tile[(w * 32 + nt * 16 + arow) * VTS + kq8];
#pragma unroll
    for (int ot = 0; ot < 12; ++ot) {
      short8 af = *(const short8*)(w2b + (size_t)(ot * 16 + arow) * 192 + ks * 32 + kq8);
#pragma unroll
      for (int nt = 0; nt < 2; ++nt)
        acc[ot][nt] = __builtin_amdgcn_mfma_f32_16x16x32_bf16(af, bf[nt], acc[ot][nt], 0, 0, 0);
    }
  }

  float* __restrict__ ob = out + ((size_t)b * 192) * 16384;
#pragma unroll
  for (int og = 0; og < 6; ++og) {
    __syncthreads();
#pragma unroll
    for (int oi = 0; oi < 2; ++oi) {
#pragma unroll
      for (int nt = 0; nt < 2; ++nt)
#pragma unroll
        for (int rr = 0; rr < 4; ++rr) {
          const int o_l = oi * 16 + (l >> 4) * 4 + rr;
          const int n_l = w * 32 + nt * 16 + (l & 15);
          cout[o_l * 132 + n_l] = acc[og * 2 + oi][nt][rr];
        }
    }
    __syncthreads();
    const int o_l = t >> 3;
    const int o   = og * 32 + o_l;
#pragma unroll
    for (int c = 0; c < 4; ++c) {
      const int n = (t & 7) * 4 + c * 32;
      float4 v4;
      v4.x = cout[o_l * 132 + n + 0];
      v4.y = cout[o_l * 132 + n + 1];
      v4.z = cout[o_l * 132 + n + 2];
      v4.w = cout[o_l * 132 + n + 3];
      *(float4*)(ob + (size_t)o * 16384 + n0 + n) = v4;
    }
  }
}

// ---------------------------------------------------------------------------
extern "C" void kernel_launch(void* const* d_in, const int* in_sizes, int n_in,
                              void* d_out, int out_size, void* d_ws, size_t ws_size,
                              hipStream_t stream)
{
  const float* x    = (const float*)d_in[0];
  const float* y    = (const float*)d_in[1];
  const float* wdw  = (const float*)d_in[2];
  const float* wp   = (const float*)d_in[3];
  const float* temp = (const float*)d_in[4];

  char* ws = (char*)d_ws;
  const size_t QK = (size_t)NB * CTOT * HW * 2;   // 50,331,648 bytes per tensor
  u16*   qws  = (u16*)(ws);
  u16*   kws  = (u16*)(ws + QK);
  u16*   vws  = (u16*)(ws + 2 * QK);
  float* gram = (float*)(ws + 3 * QK);                  // 196608
  float* sqq  = (float*)(ws + 3 * QK + 196608);         // 6144
  float* sqk  = (float*)(ws + 3 * QK + 196608 + 6144);  // 6144
  u16*   W2   = (u16*)(ws + 3 * QK + 196608 + 12288);   // 8*192*192*2
  float* out  = (float*)d_out;

  hipMemsetAsync(ws + 3 * QK, 0, 208896, stream);
  kconv<<<6144, 256, 0, stream>>>(x, y, wdw, qws, kws, vws);
  k2a_gram<<<768, 256, 0, stream>>>(qws, kws, gram, sqq, sqk);
  k2b_w2<<<48, 256, 0, stream>>>(gram, sqq, sqk, wp, temp, W2);
  k3_gemm<<<1024, 256, 0, stream>>>(W2, vws, out);
}

// Round 16
// 172.110 us; speedup vs baseline: 1.0131x; 1.0131x over previous
//
#include <hip/hip_runtime.h>
#include <hip/hip_bf16.h>

#define DEV __device__ __forceinline__

typedef unsigned char u8;
typedef unsigned short u16;
typedef unsigned int u32;
typedef long long i64;
typedef __attribute__((ext_vector_type(8))) short short8;
typedef __attribute__((ext_vector_type(4))) float f32x4;

DEV u16 f2bf(float f) {
  __hip_bfloat16 h = __float2bfloat16(f);   // RNE
  return *(u16*)&h;
}

#define NB 8
#define NH 6
#define CTOT 192
#define HW 16384
#define VTS 34     // k3 LDS n-row stride (u16): 17 dwords, coprime 32 banks
#define LSTR 136   // kconv LDS row stride (f32)

// ---------------------------------------------------------------------------
// KCONV v6: LDS-staged conv (R15 structure) + fp8 q/k emission + in-kernel
// exact f32 norms. R11-R15 showed kconv is traffic-bound at ~3.6 TB/s
// effective regardless of schedule; this cuts its write traffic 150->100 MB
// (q,k as fp8 e4m3; v stays bf16) and removes k2a's norm work.
// grid 6144 = (q|kv) x 8b x 192ch x 2 row-halves; block = 1 channel, 64 rows.
// ---------------------------------------------------------------------------
__global__ __launch_bounds__(256) void kconv(
    const float* __restrict__ x, const float* __restrict__ y,
    const float* __restrict__ wdw,
    u8* __restrict__ qws, u8* __restrict__ kws, u16* __restrict__ vws,
    float* __restrict__ sqq, float* __restrict__ sqk)
{
  __shared__ __align__(16) float lds[66 * LSTR];
  const int t = threadIdx.x, lane = t & 63, w = t >> 6;
  const int bx   = blockIdx.x;
  const int iskv = bx & 1;
  const int rest = bx >> 1;          // 0..3071
  const int chp  = rest & 1;
  const int task = rest >> 1;        // 0..1535
  const int b  = task / 192;
  const int gc = task % 192;
  const int r0 = chp * 64;

  const float* __restrict__ in =
      (iskv ? y : x) + (((size_t)(b * CTOT + gc)) << 14);

  float w0[9], w1[9];
  if (!iskv) {
#pragma unroll
    for (int i = 0; i < 9; ++i) w0[i] = wdw[gc * 9 + i];
  } else {
#pragma unroll
    for (int i = 0; i < 9; ++i) {
      w0[i] = wdw[(CTOT + gc) * 9 + i];       // k
      w1[i] = wdw[(2 * CTOT + gc) * 9 + i];   // v
    }
  }

  // zero the horizontal edge pads actually read: float 3 (px -1), 132 (px 128)
  if (t < 132) {
    const int row = t >> 1;
    lds[row * LSTR + ((t & 1) ? 132 : 3)] = 0.f;
  }
  // stage 66 rows x 128 px (f32), coalesced float4; OOB rows -> zero
#pragma unroll
  for (int i = 0; i < 9; ++i) {
    const int idx = i * 256 + t;
    if (idx < 2112) {                      // 66 rows * 32 float4
      const int row = idx >> 5, c4 = idx & 31;
      const int grow = r0 - 1 + row;
      float4 v = (grow >= 0 && grow < 128)
          ? *(const float4*)(in + grow * 128 + c4 * 4)
          : make_float4(0.f, 0.f, 0.f, 0.f);
      *(float4*)&lds[row * LSTR + 4 + c4 * 4] = v;
    }
  }
  __syncthreads();

  const int j    = lane & 31;          // px group: px 4j..4j+3
  const int half = lane >> 5;          // row parity within pair
  u8*  __restrict__ out0 =
      (iskv ? kws : qws) + (((size_t)(b * CTOT + gc)) << 14);   // 16384 B/ch
  u16* __restrict__ out1 = vws + (((size_t)(b * CTOT + gc)) << 14);

  float ssum = 0.f;    // sum of squares of class-0 outputs (q or k), exact f32

#pragma unroll
  for (int i = 0; i < 8; ++i) {
    const int lrow = w * 16 + i * 2 + half;    // local out row 0..63
    const int r = r0 + lrow;

    float  lt[3], rt[3];
    float4 md[3];
#pragma unroll
    for (int dr = 0; dr < 3; ++dr) {
      const int base = (lrow + dr) * LSTR + 4 * j;
      lt[dr] = lds[base + 3];
      md[dr] = *(const float4*)&lds[base + 4];
      rt[dr] = lds[base + 8];
    }

    // class 0 (q or k) -> fp8 e4m3, packed 4 px per u32
    {
      float o0 = 0.f, o1 = 0.f, o2 = 0.f, o3 = 0.f;
#pragma unroll
      for (int dr = 0; dr < 3; ++dr) {
        const float a = lt[dr], b0 = md[dr].x, c = md[dr].y,
                    d = md[dr].z, e = md[dr].w, f = rt[dr];
        o0 = fmaf(w0[dr * 3 + 0], a,  o0); o0 = fmaf(w0[dr * 3 + 1], b0, o0); o0 = fmaf(w0[dr * 3 + 2], c, o0);
        o1 = fmaf(w0[dr * 3 + 0], b0, o1); o1 = fmaf(w0[dr * 3 + 1], c,  o1); o1 = fmaf(w0[dr * 3 + 2], d, o1);
        o2 = fmaf(w0[dr * 3 + 0], c,  o2); o2 = fmaf(w0[dr * 3 + 1], d,  o2); o2 = fmaf(w0[dr * 3 + 2], e, o2);
        o3 = fmaf(w0[dr * 3 + 0], d,  o3); o3 = fmaf(w0[dr * 3 + 1], e,  o3); o3 = fmaf(w0[dr * 3 + 2], f, o3);
      }
      ssum = fmaf(o0, o0, ssum); ssum = fmaf(o1, o1, ssum);
      ssum = fmaf(o2, o2, ssum); ssum = fmaf(o3, o3, ssum);
      u32 p = (u32)__builtin_amdgcn_cvt_pk_fp8_f32(o0, o1, 0, false);
      p = (u32)__builtin_amdgcn_cvt_pk_fp8_f32(o2, o3, (int)p, true);
      *(u32*)(out0 + r * 128 + 4 * j) = p;
    }
    // class 1 (v), kv blocks only -> bf16
    if (iskv) {
      float o0 = 0.f, o1 = 0.f, o2 = 0.f, o3 = 0.f;
#pragma unroll
      for (int dr = 0; dr < 3; ++dr) {
        const float a = lt[dr], b0 = md[dr].x, c = md[dr].y,
                    d = md[dr].z, e = md[dr].w, f = rt[dr];
        o0 = fmaf(w1[dr * 3 + 0], a,  o0); o0 = fmaf(w1[dr * 3 + 1], b0, o0); o0 = fmaf(w1[dr * 3 + 2], c, o0);
        o1 = fmaf(w1[dr * 3 + 0], b0, o1); o1 = fmaf(w1[dr * 3 + 1], c,  o1); o1 = fmaf(w1[dr * 3 + 2], d, o1);
        o2 = fmaf(w1[dr * 3 + 0], c,  o2); o2 = fmaf(w1[dr * 3 + 1], d,  o2); o2 = fmaf(w1[dr * 3 + 2], e, o2);
        o3 = fmaf(w1[dr * 3 + 0], d,  o3); o3 = fmaf(w1[dr * 3 + 1], e,  o3); o3 = fmaf(w1[dr * 3 + 2], f, o3);
      }
      const u32 p01 = ((u32)f2bf(o1) << 16) | (u32)f2bf(o0);
      const u32 p23 = ((u32)f2bf(o3) << 16) | (u32)f2bf(o2);
      *(uint2*)(out1 + r * 128 + 4 * j) = make_uint2(p01, p23);
    }
  }

  // exact f32 norm accumulation: wave butterfly-reduce + one atomic per wave
  ssum += __shfl_xor(ssum, 1);
  ssum += __shfl_xor(ssum, 2);
  ssum += __shfl_xor(ssum, 4);
  ssum += __shfl_xor(ssum, 8);
  ssum += __shfl_xor(ssum, 16);
  ssum += __shfl_xor(ssum, 32);
  if (lane == 0)
    atomicAdd((iskv ? sqk : sqq) + b * CTOT + gc, ssum);
}

// ---------------------------------------------------------------------------
// K2a (fp8): per (b,head) gram[c][d] = sum_n q[c][n]*k[d][n] via
// mfma_f32_16x16x32_fp8_fp8 (i64 fragments = 8 fp8/lane). Dot products are
// permutation-invariant in k, so the bf16-verified addressing carries over.
// Norms now come from kconv. grid 48x16 p-tiles, f32-atomic partials.
// ---------------------------------------------------------------------------
__global__ __launch_bounds__(256) void k2a_gram(
    const u8* __restrict__ qws, const u8* __restrict__ kws,
    float* __restrict__ gram)
{
  const int t = threadIdx.x, l = t & 63, w = t >> 6;
  const int bh = blockIdx.x >> 4, tile = blockIdx.x & 15;
  const int p0 = tile * 1024 + w * 256;
  const u8* qb = qws + (((size_t)bh) << 19);   // bh * 32ch * 16384B
  const u8* kb = kws + (((size_t)bh) << 19);
  const int row = l & 15;
  const int kq  = (l >> 4) * 8;

  f32x4 acc[2][2] = {};

  for (int ks = 0; ks < 8; ++ks) {
    const int p = p0 + ks * 32 + kq;
    i64 av[2], bv[2];
#pragma unroll
    for (int tc = 0; tc < 2; ++tc) {
      av[tc] = *(const i64*)(qb + (((size_t)(tc * 16 + row)) << 14) + p);
      bv[tc] = *(const i64*)(kb + (((size_t)(tc * 16 + row)) << 14) + p);
    }
#pragma unroll
    for (int tc = 0; tc < 2; ++tc)
#pragma unroll
      for (int td = 0; td < 2; ++td)
        acc[tc][td] = __builtin_amdgcn_mfma_f32_16x16x32_fp8_fp8(av[tc], bv[td], acc[tc][td], 0, 0, 0);
  }

#pragma unroll
  for (int tc = 0; tc < 2; ++tc)
#pragma unroll
    for (int td = 0; td < 2; ++td)
#pragma unroll
      for (int rr = 0; rr < 4; ++rr) {
        int c = tc * 16 + (l >> 4) * 4 + rr;
        int d = td * 16 + row;
        atomicAdd(gram + (size_t)bh * 1024 + c * 32 + d, acc[tc][td][rr]);
      }
}

// ---------------------------------------------------------------------------
// K2b: logits = gram/(|q||k|)*temp, row-softmax, fold 1x1 proj:
//   W2[b][o][h*32+d] = sum_c wp[o][h*32+c] * A[c][d]  (bf16 out)
// ---------------------------------------------------------------------------
__global__ __launch_bounds__(256) void k2b_w2(
    const float* __restrict__ gram, const float* __restrict__ sqq,
    const float* __restrict__ sqk, const float* __restrict__ wp,
    const float* __restrict__ temp, u16* __restrict__ W2)
{
  __shared__ float Ls[32][33];
  __shared__ float As[32][33];
  __shared__ float wl[192 * 32];
  __shared__ float nq[32], nk[32];
  const int t = threadIdx.x;
  const int bh = blockIdx.x, b = bh / 6, h = bh % 6;
  const float tmp = temp[h];
  if (t < 32) nq[t] = fmaxf(sqrtf(sqq[bh * 32 + t]), 1e-12f);
  else if (t < 64) nk[t - 32] = fmaxf(sqrtf(sqk[bh * 32 + t - 32]), 1e-12f);
  __syncthreads();
#pragma unroll
  for (int i = 0; i < 4; ++i) {
    int idx = i * 256 + t, c = idx >> 5, d = idx & 31;
    Ls[c][d] = gram[(size_t)bh * 1024 + idx] / (nq[c] * nk[d]) * tmp;
  }
  __syncthreads();
  if (t < 32) {
    float m = -1e30f;
#pragma unroll
    for (int d = 0; d < 32; ++d) m = fmaxf(m, Ls[t][d]);
    float s = 0.f;
#pragma unroll
    for (int d = 0; d < 32; ++d) s += expf(Ls[t][d] - m);
    float inv = 1.0f / s;
#pragma unroll
    for (int d = 0; d < 32; ++d) As[t][d] = expf(Ls[t][d] - m) * inv;
  }
  for (int i = 0; i < 24; ++i) {
    int idx = i * 256 + t, o = idx >> 5, c = idx & 31;
    wl[idx] = wp[o * 192 + h * 32 + c];
  }
  __syncthreads();
  for (int i = 0; i < 24; ++i) {
    int idx = i * 256 + t, o = idx >> 5, d = idx & 31;
    float a = 0.f;
#pragma unroll
    for (int c = 0; c < 32; ++c) a = fmaf(wl[o * 32 + c], As[c][d], a);
    W2[((size_t)(b * 192 + o)) * 192 + h * 32 + d] = f2bf(a);
  }
}

// ---------------------------------------------------------------------------
// K3: out[b][o][n] = sum_c W2[b][o][c] * v[b][c][n], MFMA 16x16x32 bf16.
// v in natural [b][c][n]; per ks-step stage 32x128 tile -> LDS transpose.
// Epilogue: LDS-transpose C so global stores are contiguous float4 runs.
// ---------------------------------------------------------------------------
__global__ __launch_bounds__(256) void k3_gemm(
    const u16* __restrict__ W2, const u16* __restrict__ vnat,
    float* __restrict__ out)
{
  __shared__ __align__(16) u16 b_tile[128 * VTS];
  __shared__ __align__(16) float cout[32 * 132];
  const int t = threadIdx.x, l = t & 63, w = t >> 6;
  const int bx = blockIdx.x;
  const int b  = bx >> 7, nb = bx & 127;
  const int arow = l & 15;
  const int kq8  = (l >> 4) * 8;
  const u16* w2b = W2 + (size_t)b * 192 * 192;
  const u16* vb  = vnat + ((size_t)b * CTOT) * HW;
  const int n0 = nb * 128;

  f32x4 acc[12][2] = {};

  for (int ks = 0; ks < 6; ++ks) {
    if (ks > 0) __syncthreads();
#pragma unroll
    for (int r2 = 0; r2 < 2; ++r2) {
      const int ch   = (t >> 4) + r2 * 16;
      const int nseg = (t & 15) * 8;
      short8 vv = *(const short8*)(vb + (size_t)(ks * 32 + ch) * HW + n0 + nseg);
#pragma unroll
      for (int j = 0; j < 8; ++j) b_tile[(nseg + j) * VTS + ch] = (u16)vv[j];
    }
    __syncthreads();

    short8 bf[2];
#pragma unroll
    for (int nt = 0; nt < 2; ++nt)
      bf[nt] = *(const short8*)&b_tile[(w * 32 + nt * 16 + arow) * VTS + kq8];
#pragma unroll
    for (int ot = 0; ot < 12; ++ot) {
      short8 af = *(const short8*)(w2b + (size_t)(ot * 16 + arow) * 192 + ks * 32 + kq8);
#pragma unroll
      for (int nt = 0; nt < 2; ++nt)
        acc[ot][nt] = __builtin_amdgcn_mfma_f32_16x16x32_bf16(af, bf[nt], acc[ot][nt], 0, 0, 0);
    }
  }

  float* __restrict__ ob = out + ((size_t)b * 192) * 16384;
#pragma unroll
  for (int og = 0; og < 6; ++og) {
    __syncthreads();
#pragma unroll
    for (int oi = 0; oi < 2; ++oi) {
#pragma unroll
      for (int nt = 0; nt < 2; ++nt)
#pragma unroll
        for (int rr = 0; rr < 4; ++rr) {
          const int o_l = oi * 16 + (l >> 4) * 4 + rr;
          const int n_l = w * 32 + nt * 16 + (l & 15);
          cout[o_l * 132 + n_l] = acc[og * 2 + oi][nt][rr];
        }
    }
    __syncthreads();
    const int o_l = t >> 3;
    const int o   = og * 32 + o_l;
#pragma unroll
    for (int c = 0; c < 4; ++c) {
      const int n = (t & 7) * 4 + c * 32;
      float4 v4;
      v4.x = cout[o_l * 132 + n + 0];
      v4.y = cout[o_l * 132 + n + 1];
      v4.z = cout[o_l * 132 + n + 2];
      v4.w = cout[o_l * 132 + n + 3];
      *(float4*)(ob + (size_t)o * 16384 + n0 + n) = v4;
    }
  }
}

// ---------------------------------------------------------------------------
extern "C" void kernel_launch(void* const* d_in, const int* in_sizes, int n_in,
                              void* d_out, int out_size, void* d_ws, size_t ws_size,
                              hipStream_t stream)
{
  const float* x    = (const float*)d_in[0];
  const float* y    = (const float*)d_in[1];
  const float* wdw  = (const float*)d_in[2];
  const float* wp   = (const float*)d_in[3];
  const float* temp = (const float*)d_in[4];

  char* ws = (char*)d_ws;
  const size_t QK8 = (size_t)NB * CTOT * HW;       // 25,165,824 B (fp8)
  const size_t VBF = (size_t)NB * CTOT * HW * 2;   // 50,331,648 B (bf16)
  u8*    qws  = (u8*)(ws);
  u8*    kws  = (u8*)(ws + QK8);
  u16*   vws  = (u16*)(ws + 2 * QK8);
  char*  meta = ws + 2 * QK8 + VBF;
  float* gram = (float*)(meta);                    // 196608
  float* sqq  = (float*)(meta + 196608);           // 6144
  float* sqk  = (float*)(meta + 196608 + 6144);    // 6144
  u16*   W2   = (u16*)(meta + 196608 + 12288);     // 8*192*192*2
  float* out  = (float*)d_out;

  hipMemsetAsync(meta, 0, 208896, stream);
  kconv<<<6144, 256, 0, stream>>>(x, y, wdw, qws, kws, vws, sqq, sqk);
  k2a_gram<<<768, 256, 0, stream>>>(qws, kws, gram);
  k2b_w2<<<48, 256, 0, stream>>>(gram, sqq, sqk, wp, temp, W2);
  k3_gemm<<<1024, 256, 0, stream>>>(W2, vws, out);
}